// Round 1
// baseline (2149.037 us; speedup 1.0000x reference)
//
#include <hip/hip_runtime.h>
#include <hip/hip_bf16.h>

#define N_POI  100000
#define N_USER 20000
#define NNZ    300000
#define EMB    256

// Zero a float buffer.
__global__ void zero_kernel(float* __restrict__ p, size_t n) {
    size_t i = (size_t)blockIdx.x * blockDim.x + threadIdx.x;
    size_t stride = (size_t)gridDim.x * blockDim.x;
    for (; i < n; i += stride) p[i] = 0.0f;
}

// COO SpMM via atomic scatter-add. One 64-lane wave per edge; each lane
// handles a float4 chunk of the 256-dim row (64 * 4 = 256).
__global__ void spmm_atomic_kernel(const int* __restrict__ rows,
                                   const int* __restrict__ cols,
                                   const float* __restrict__ vals,
                                   const float* __restrict__ dense,
                                   float* __restrict__ out,
                                   int nnz) {
    int gid  = blockIdx.x * blockDim.x + threadIdx.x;
    int edge = gid >> 6;   // wave per edge
    int lane = gid & 63;
    if (edge >= nnz) return;

    int   r = rows[edge];
    int   c = cols[edge];
    float v = vals[edge];

    const float4* src = reinterpret_cast<const float4*>(dense + (size_t)c * EMB) + lane;
    float4 m = *src;

    float* dst = out + (size_t)r * EMB + (size_t)lane * 4;
    atomicAdd(dst + 0, v * m.x);
    atomicAdd(dst + 1, v * m.y);
    atomicAdd(dst + 2, v * m.z);
    atomicAdd(dst + 3, v * m.w);
}

extern "C" void kernel_launch(void* const* d_in, const int* in_sizes, int n_in,
                              void* d_out, int out_size, void* d_ws, size_t ws_size,
                              hipStream_t stream) {
    const float* pois_embs = (const float*)d_in[0];
    const int*   up_rows   = (const int*)d_in[1];
    const int*   up_cols   = (const int*)d_in[2];
    const float* up_vals   = (const float*)d_in[3];
    const int*   pu_rows   = (const int*)d_in[4];
    const int*   pu_cols   = (const int*)d_in[5];
    const float* pu_vals   = (const float*)d_in[6];

    float* out = (float*)d_out;                     // [N_POI, EMB]
    float* msg = (float*)d_ws;                      // [N_USER, EMB] intermediate

    const size_t msg_elems = (size_t)N_USER * EMB;  // 5.12M floats = 20.5 MB
    const size_t out_elems = (size_t)N_POI * EMB;   // 25.6M floats

    // Zero scatter targets (harness poisons them to 0xAA).
    zero_kernel<<<2048, 256, 0, stream>>>(msg, msg_elems);
    zero_kernel<<<2048, 256, 0, stream>>>(out, out_elems);

    // hop 1: msg[N_USER] += up_vals * pois_embs[up_cols]
    {
        int total_threads = NNZ * 64;
        int blocks = (total_threads + 255) / 256;
        spmm_atomic_kernel<<<blocks, 256, 0, stream>>>(
            up_rows, up_cols, up_vals, pois_embs, msg, NNZ);
    }

    // hop 2: out[N_POI] += pu_vals * msg[pu_cols]
    {
        int total_threads = NNZ * 64;
        int blocks = (total_threads + 255) / 256;
        spmm_atomic_kernel<<<blocks, 256, 0, stream>>>(
            pu_rows, pu_cols, pu_vals, msg, out, NNZ);
    }
}

// Round 2
// 392.672 us; speedup vs baseline: 5.4729x; 5.4729x over previous
//
#include <hip/hip_runtime.h>
#include <hip/hip_bf16.h>

#define N_POI  100000
#define N_USER 20000
#define NNZ    300000
#define EMB    256

// ---------- CSR build helpers ----------

__global__ void zero_ints(int* __restrict__ p, int n) {
    int i = blockIdx.x * blockDim.x + threadIdx.x;
    int s = gridDim.x * blockDim.x;
    for (; i < n; i += s) p[i] = 0;
}

__global__ void count_kernel(const int* __restrict__ rows, int* __restrict__ cnt, int nnz) {
    int i = blockIdx.x * blockDim.x + threadIdx.x;
    int s = gridDim.x * blockDim.x;
    for (; i < nnz; i += s) atomicAdd(&cnt[rows[i]], 1);
}

// Allocate disjoint segments: start[r] = fetch_add(cursor, cnt[r]).
// Offsets need not be in row order -- eidx stores explicit edge ids.
__global__ void alloc_kernel(const int* __restrict__ cnt, int* __restrict__ start,
                             int* __restrict__ cursor, int n) {
    int i = blockIdx.x * blockDim.x + threadIdx.x;
    int s = gridDim.x * blockDim.x;
    for (; i < n; i += s) start[i] = atomicAdd(cursor, cnt[i]);
}

__global__ void fill_kernel(const int* __restrict__ rows, const int* __restrict__ start,
                            int* __restrict__ fill, int* __restrict__ eidx, int nnz) {
    int i = blockIdx.x * blockDim.x + threadIdx.x;
    int s = gridDim.x * blockDim.x;
    for (; i < nnz; i += s) {
        int r = rows[i];
        int p = atomicAdd(&fill[r], 1);
        eidx[start[r] + p] = i;
    }
}

// ---------- pull-based gather: one 64-lane wave per output row ----------
// Each lane accumulates a float4 chunk (64 lanes * 4 = 256 dims) in registers,
// then writes the row once, coalesced. No fp32 atomics anywhere.

__global__ void gather_kernel(const int* __restrict__ start, const int* __restrict__ cnt,
                              const int* __restrict__ eidx, const int* __restrict__ cols,
                              const float* __restrict__ vals, const float* __restrict__ dense,
                              float* __restrict__ out, int n_rows) {
    int gid  = blockIdx.x * blockDim.x + threadIdx.x;
    int row  = gid >> 6;
    int lane = gid & 63;
    if (row >= n_rows) return;

    int s = start[row];
    int c = cnt[row];

    float4 acc = make_float4(0.f, 0.f, 0.f, 0.f);
    for (int k = 0; k < c; ++k) {
        int   e   = eidx[s + k];          // wave-uniform loads (L1 broadcast)
        int   col = cols[e];
        float v   = vals[e];
        const float4 m = *(reinterpret_cast<const float4*>(dense + (size_t)col * EMB) + lane);
        acc.x += v * m.x;
        acc.y += v * m.y;
        acc.z += v * m.z;
        acc.w += v * m.w;
    }
    *(reinterpret_cast<float4*>(out + (size_t)row * EMB) + lane) = acc;
}

// ---------- launch ----------

extern "C" void kernel_launch(void* const* d_in, const int* in_sizes, int n_in,
                              void* d_out, int out_size, void* d_ws, size_t ws_size,
                              hipStream_t stream) {
    const float* pois_embs = (const float*)d_in[0];
    const int*   up_rows   = (const int*)d_in[1];
    const int*   up_cols   = (const int*)d_in[2];
    const float* up_vals   = (const float*)d_in[3];
    const int*   pu_rows   = (const int*)d_in[4];
    const int*   pu_cols   = (const int*)d_in[5];
    const float* pu_vals   = (const float*)d_in[6];

    float* out = (float*)d_out;   // [N_POI, EMB]

    // ---- workspace layout ----
    char* ws = (char*)d_ws;
    size_t off = 0;
    auto take = [&](size_t bytes) { char* p = ws + off; off += (bytes + 15) & ~size_t(15); return p; };

    float* msg      = (float*)take((size_t)N_USER * EMB * sizeof(float)); // 20.48 MB
    // contiguous int control region (zeroed in one kernel)
    int* ctrl       = (int*)take((size_t)(3 * N_USER + 3 * N_POI + 2) * sizeof(int));
    int* up_cnt     = ctrl;
    int* up_start   = up_cnt + N_USER;
    int* up_fill    = up_start + N_USER;
    int* pu_cnt     = up_fill + N_USER;
    int* pu_start   = pu_cnt + N_POI;
    int* pu_fill    = pu_start + N_POI;
    int* cursors    = pu_fill + N_POI;            // [0]=up, [1]=pu
    int* up_eidx    = (int*)take((size_t)NNZ * sizeof(int));
    int* pu_eidx    = (int*)take((size_t)NNZ * sizeof(int));

    const int ctrl_n = 3 * N_USER + 3 * N_POI + 2;

    // ---- build CSR for both hops ----
    zero_ints<<<512, 256, 0, stream>>>(ctrl, ctrl_n);

    count_kernel<<<1024, 256, 0, stream>>>(up_rows, up_cnt, NNZ);
    count_kernel<<<1024, 256, 0, stream>>>(pu_rows, pu_cnt, NNZ);

    alloc_kernel<<<256, 256, 0, stream>>>(up_cnt, up_start, &cursors[0], N_USER);
    alloc_kernel<<<512, 256, 0, stream>>>(pu_cnt, pu_start, &cursors[1], N_POI);

    fill_kernel<<<1024, 256, 0, stream>>>(up_rows, up_start, up_fill, up_eidx, NNZ);
    fill_kernel<<<1024, 256, 0, stream>>>(pu_rows, pu_start, pu_fill, pu_eidx, NNZ);

    // ---- hop 1: msg[user] = sum up_vals * pois_embs[up_cols] ----
    {
        int blocks = (N_USER * 64 + 255) / 256;   // wave per row
        gather_kernel<<<blocks, 256, 0, stream>>>(
            up_start, up_cnt, up_eidx, up_cols, up_vals, pois_embs, msg, N_USER);
    }

    // ---- hop 2: out[poi] = sum pu_vals * msg[pu_cols] ----
    {
        int blocks = (N_POI * 64 + 255) / 256;
        gather_kernel<<<blocks, 256, 0, stream>>>(
            pu_start, pu_cnt, pu_eidx, pu_cols, pu_vals, msg, out, N_POI);
    }
}

// Round 3
// 342.902 us; speedup vs baseline: 6.2672x; 1.1451x over previous
//
#include <hip/hip_runtime.h>
#include <hip/hip_bf16.h>

#define N_POI  100000
#define N_USER 20000
#define NNZ    300000
#define EMB    256

// ---------- CSR build (both hops fused per stage) ----------

__global__ void zero_ints(int* __restrict__ p, int n) {
    int i = blockIdx.x * blockDim.x + threadIdx.x;
    int s = gridDim.x * blockDim.x;
    for (; i < n; i += s) p[i] = 0;
}

__global__ void count_both(const int* __restrict__ up_rows, int* __restrict__ up_cnt,
                           const int* __restrict__ pu_rows, int* __restrict__ pu_cnt) {
    int i = blockIdx.x * blockDim.x + threadIdx.x;
    int s = gridDim.x * blockDim.x;
    for (; i < 2 * NNZ; i += s) {
        if (i < NNZ) atomicAdd(&up_cnt[up_rows[i]], 1);
        else         atomicAdd(&pu_cnt[pu_rows[i - NNZ]], 1);
    }
}

// start[r] = fetch_add(cursor, round4(cnt[r])) -- disjoint, 4-aligned segments.
__global__ void alloc_both(const int* __restrict__ up_cnt, int* __restrict__ up_start,
                           const int* __restrict__ pu_cnt, int* __restrict__ pu_start,
                           int* __restrict__ cursors) {
    int i = blockIdx.x * blockDim.x + threadIdx.x;
    int s = gridDim.x * blockDim.x;
    for (; i < N_USER + N_POI; i += s) {
        if (i < N_USER) up_start[i] = atomicAdd(&cursors[0], (up_cnt[i] + 3) & ~3);
        else {
            int r = i - N_USER;
            pu_start[r] = atomicAdd(&cursors[1], (pu_cnt[r] + 3) & ~3);
        }
    }
}

// Reorder (col,val) into per-row segments -- no eidx indirection at gather time.
__global__ void fill_both(const int* __restrict__ up_rows, const int* __restrict__ up_cols,
                          const float* __restrict__ up_vals, const int* __restrict__ up_start,
                          int* __restrict__ up_fill, int* __restrict__ up_cols_r,
                          float* __restrict__ up_vals_r,
                          const int* __restrict__ pu_rows, const int* __restrict__ pu_cols,
                          const float* __restrict__ pu_vals, const int* __restrict__ pu_start,
                          int* __restrict__ pu_fill, int* __restrict__ pu_cols_r,
                          float* __restrict__ pu_vals_r) {
    int i = blockIdx.x * blockDim.x + threadIdx.x;
    int s = gridDim.x * blockDim.x;
    for (; i < 2 * NNZ; i += s) {
        if (i < NNZ) {
            int r = up_rows[i];
            int p = atomicAdd(&up_fill[r], 1);
            int d = up_start[r] + p;
            up_cols_r[d] = up_cols[i];
            up_vals_r[d] = up_vals[i];
        } else {
            int e = i - NNZ;
            int r = pu_rows[e];
            int p = atomicAdd(&pu_fill[r], 1);
            int d = pu_start[r] + p;
            pu_cols_r[d] = pu_cols[e];
            pu_vals_r[d] = pu_vals[e];
        }
    }
}

// ---------- pull gather: one 64-lane wave per row, 4-wide unrolled ----------
// Per quad: one int4 (cols) + one float4 (vals) uniform load, then 4
// INDEPENDENT 1KB row gathers in flight (vs 1 in the serial version).

__global__ void gather_kernel(const int* __restrict__ start, const int* __restrict__ cnt,
                              const int* __restrict__ cols_r, const float* __restrict__ vals_r,
                              const float* __restrict__ dense, float* __restrict__ out,
                              int n_rows) {
    int gid  = blockIdx.x * blockDim.x + threadIdx.x;
    int row  = gid >> 6;
    int lane = gid & 63;
    if (row >= n_rows) return;

    int s = start[row];
    int c = cnt[row];

    float4 acc = make_float4(0.f, 0.f, 0.f, 0.f);
    int k = 0;
    for (; k + 4 <= c; k += 4) {
        int4   c4 = *reinterpret_cast<const int4*>(cols_r + s + k);     // 16B-aligned
        float4 v4 = *reinterpret_cast<const float4*>(vals_r + s + k);
        const float4 m0 = *(reinterpret_cast<const float4*>(dense + (size_t)c4.x * EMB) + lane);
        const float4 m1 = *(reinterpret_cast<const float4*>(dense + (size_t)c4.y * EMB) + lane);
        const float4 m2 = *(reinterpret_cast<const float4*>(dense + (size_t)c4.z * EMB) + lane);
        const float4 m3 = *(reinterpret_cast<const float4*>(dense + (size_t)c4.w * EMB) + lane);
        acc.x += v4.x * m0.x + v4.y * m1.x + v4.z * m2.x + v4.w * m3.x;
        acc.y += v4.x * m0.y + v4.y * m1.y + v4.z * m2.y + v4.w * m3.y;
        acc.z += v4.x * m0.z + v4.y * m1.z + v4.z * m2.z + v4.w * m3.z;
        acc.w += v4.x * m0.w + v4.y * m1.w + v4.z * m2.w + v4.w * m3.w;
    }
    for (; k < c; ++k) {
        int   col = cols_r[s + k];
        float v   = vals_r[s + k];
        const float4 m = *(reinterpret_cast<const float4*>(dense + (size_t)col * EMB) + lane);
        acc.x += v * m.x;
        acc.y += v * m.y;
        acc.z += v * m.z;
        acc.w += v * m.w;
    }
    *(reinterpret_cast<float4*>(out + (size_t)row * EMB) + lane) = acc;
}

// ---------- launch ----------

extern "C" void kernel_launch(void* const* d_in, const int* in_sizes, int n_in,
                              void* d_out, int out_size, void* d_ws, size_t ws_size,
                              hipStream_t stream) {
    const float* pois_embs = (const float*)d_in[0];
    const int*   up_rows   = (const int*)d_in[1];
    const int*   up_cols   = (const int*)d_in[2];
    const float* up_vals   = (const float*)d_in[3];
    const int*   pu_rows   = (const int*)d_in[4];
    const int*   pu_cols   = (const int*)d_in[5];
    const float* pu_vals   = (const float*)d_in[6];

    float* out = (float*)d_out;   // [N_POI, EMB]

    // ---- workspace layout ----
    char* ws = (char*)d_ws;
    size_t off = 0;
    auto take = [&](size_t bytes) { char* p = ws + off; off += (bytes + 15) & ~size_t(15); return p; };

    float* msg    = (float*)take((size_t)N_USER * EMB * sizeof(float));   // 20.48 MB
    int*   ctrl   = (int*)take((size_t)(3 * N_USER + 3 * N_POI + 2) * sizeof(int));
    int* up_cnt   = ctrl;
    int* up_start = up_cnt + N_USER;
    int* up_fill  = up_start + N_USER;
    int* pu_cnt   = up_fill + N_USER;
    int* pu_start = pu_cnt + N_POI;
    int* pu_fill  = pu_start + N_POI;
    int* cursors  = pu_fill + N_POI;                  // [0]=up, [1]=pu

    const int up_cap = NNZ + 4 * N_USER;              // rounded-segment capacity
    const int pu_cap = NNZ + 4 * N_POI;
    int*   up_cols_r = (int*)  take((size_t)up_cap * sizeof(int));
    float* up_vals_r = (float*)take((size_t)up_cap * sizeof(float));
    int*   pu_cols_r = (int*)  take((size_t)pu_cap * sizeof(int));
    float* pu_vals_r = (float*)take((size_t)pu_cap * sizeof(float));

    const int ctrl_n = 3 * N_USER + 3 * N_POI + 2;

    // ---- build segments for both hops (3 dispatches) ----
    zero_ints<<<512, 256, 0, stream>>>(ctrl, ctrl_n);
    count_both<<<1024, 256, 0, stream>>>(up_rows, up_cnt, pu_rows, pu_cnt);
    alloc_both<<<512, 256, 0, stream>>>(up_cnt, up_start, pu_cnt, pu_start, cursors);
    fill_both<<<1024, 256, 0, stream>>>(
        up_rows, up_cols, up_vals, up_start, up_fill, up_cols_r, up_vals_r,
        pu_rows, pu_cols, pu_vals, pu_start, pu_fill, pu_cols_r, pu_vals_r);

    // ---- hop 1: msg[user] = sum up_vals * pois_embs[up_cols] ----
    gather_kernel<<<(N_USER * 64) / 256, 256, 0, stream>>>(
        up_start, up_cnt, up_cols_r, up_vals_r, pois_embs, msg, N_USER);

    // ---- hop 2: out[poi] = sum pu_vals * msg[pu_cols] ----
    gather_kernel<<<(N_POI * 64) / 256, 256, 0, stream>>>(
        pu_start, pu_cnt, pu_cols_r, pu_vals_r, msg, out, N_POI);
}